// Round 1
// baseline (319.567 us; speedup 1.0000x reference)
//
#include <hip/hip_runtime.h>

typedef __bf16 bf16x8 __attribute__((ext_vector_type(8)));
typedef float f32x4 __attribute__((ext_vector_type(4)));

constexpr int S_LEN = 2048;
constexpr int QKV1  = 2 * 16 * 2048 * 64;   // elements per Q/K/V tensor = 4194304

__device__ inline unsigned short f2bf(float f) {
    __bf16 h = (__bf16)f;
    return __builtin_bit_cast(unsigned short, h);
}

// ---------------------------------------------------------------------------
// Kernel 1: QKV projection.  X[4096][1024] fp32 x W[1024][3072] fp32 (+bias)
//   -> Q,K,V bf16, each [B=2][H=16][S=2048][K=64], Q pre-scaled by 0.125.
// 128x128 tile, BK=32, 4 waves (2x2), each wave 64x64 via 4x4 16x16x32 MFMA.
// ---------------------------------------------------------------------------
__global__ __launch_bounds__(256) void qkv_gemm(
    const float* __restrict__ X, const float* __restrict__ W,
    const float* __restrict__ bq, unsigned short* __restrict__ qkv)
{
    __shared__ unsigned short As[128][40];   // [m][k], pad 40 (80B rows)
    __shared__ unsigned short Bs[128][40];   // [n][k] (transposed store)
    const int tid  = threadIdx.x;
    const int lane = tid & 63, wid = tid >> 6;
    const int wr = wid >> 1, wc = wid & 1;
    const int m0 = blockIdx.y * 128, n0 = blockIdx.x * 128;

    f32x4 acc[4][4];
    #pragma unroll
    for (int i = 0; i < 4; ++i)
        #pragma unroll
        for (int j = 0; j < 4; ++j) acc[i][j] = (f32x4){0.f, 0.f, 0.f, 0.f};

    for (int k0 = 0; k0 < 1024; k0 += 32) {
        #pragma unroll
        for (int p = 0; p < 4; ++p) {            // A tile 128x32
            int e = p * 1024 + tid * 4;
            int row = e >> 5, col = e & 31;
            float4 v = *(const float4*)&X[(size_t)(m0 + row) * 1024 + k0 + col];
            ushort4 u;
            u.x = f2bf(v.x); u.y = f2bf(v.y); u.z = f2bf(v.z); u.w = f2bf(v.w);
            *(ushort4*)&As[row][col] = u;
        }
        #pragma unroll
        for (int p = 0; p < 4; ++p) {            // B tile 32x128 -> Bs[n][k]
            int e = p * 1024 + tid * 4;
            int n = e & 127, kk = e >> 7;
            float4 v = *(const float4*)&W[(size_t)(k0 + kk) * 3072 + n0 + n];
            Bs[n + 0][kk] = f2bf(v.x);
            Bs[n + 1][kk] = f2bf(v.y);
            Bs[n + 2][kk] = f2bf(v.z);
            Bs[n + 3][kk] = f2bf(v.w);
        }
        __syncthreads();
        bf16x8 a[4], b[4];
        #pragma unroll
        for (int mi = 0; mi < 4; ++mi)
            a[mi] = *(const bf16x8*)&As[wr * 64 + mi * 16 + (lane & 15)][(lane >> 4) * 8];
        #pragma unroll
        for (int ni = 0; ni < 4; ++ni)
            b[ni] = *(const bf16x8*)&Bs[wc * 64 + ni * 16 + (lane & 15)][(lane >> 4) * 8];
        #pragma unroll
        for (int mi = 0; mi < 4; ++mi)
            #pragma unroll
            for (int ni = 0; ni < 4; ++ni)
                acc[mi][ni] = __builtin_amdgcn_mfma_f32_16x16x32_bf16(a[mi], b[ni], acc[mi][ni], 0, 0, 0);
        __syncthreads();
    }

    #pragma unroll
    for (int mi = 0; mi < 4; ++mi)
        #pragma unroll
        for (int ni = 0; ni < 4; ++ni)
            #pragma unroll
            for (int r = 0; r < 4; ++r) {
                int m = m0 + wr * 64 + mi * 16 + (lane >> 4) * 4 + r;
                int n = n0 + wc * 64 + ni * 16 + (lane & 15);
                float v = acc[mi][ni][r] + bq[n];
                int t = n >> 10, rem = n & 1023;
                if (t == 0) v *= 0.125f;          // q * rsqrt(64)
                int h = rem >> 6, kk = rem & 63;
                int bb = m >> 11, s = m & 2047;
                qkv[(size_t)t * QKV1 + ((size_t)(bb * 16 + h) * 2048 + s) * 64 + kk] = f2bf(v);
            }
}

// ---------------------------------------------------------------------------
// Kernel 2: causal flash attention. Block = (64 q-rows) x (one b,h).
// 4 waves x 16 q-rows. KV tiles of 64. Online softmax in registers.
// ---------------------------------------------------------------------------
__global__ __launch_bounds__(256) void attn_fwd(
    const unsigned short* __restrict__ qkv, unsigned short* __restrict__ aout)
{
    __shared__ unsigned short Ks[64][72];       // [kv][k]   (144B rows, 16B aligned)
    __shared__ unsigned short Vs[64][72];       // [k][kv]   (transposed)
    __shared__ unsigned short Ps[4][16][72];    // per-wave P strip [qrow][kv]
    const int tid = threadIdx.x, lane = tid & 63, wid = tid >> 6;
    const int qb = blockIdx.x, bh = blockIdx.y;
    const int q0 = qb * 64;
    const unsigned short* Qg = qkv + (size_t)bh * S_LEN * 64;
    const unsigned short* Kg = qkv + (size_t)QKV1 + (size_t)bh * S_LEN * 64;
    const unsigned short* Vg = qkv + 2 * (size_t)QKV1 + (size_t)bh * S_LEN * 64;

    // Q fragments (A-operand: row = lane&15, k = (lane>>4)*8 + i)
    const int qrow_a = q0 + wid * 16 + (lane & 15);
    bf16x8 qf0 = *(const bf16x8*)&Qg[(size_t)qrow_a * 64 + (lane >> 4) * 8];
    bf16x8 qf1 = *(const bf16x8*)&Qg[(size_t)qrow_a * 64 + 32 + (lane >> 4) * 8];

    f32x4 oacc[4];
    #pragma unroll
    for (int i = 0; i < 4; ++i) oacc[i] = (f32x4){0.f, 0.f, 0.f, 0.f};
    float mrow[4], lrow[4];
    #pragma unroll
    for (int r = 0; r < 4; ++r) { mrow[r] = -1e30f; lrow[r] = 0.f; }

    for (int jb = 0; jb <= qb; ++jb) {
        const int j0 = jb * 64;
        {   // stage K (direct) and V (transposed)
            int row = tid >> 2, cg = tid & 3;
            #pragma unroll
            for (int i = 0; i < 4; ++i) {
                ushort4 k4 = *(const ushort4*)&Kg[(size_t)(j0 + row) * 64 + cg * 16 + i * 4];
                *(ushort4*)&Ks[row][cg * 16 + i * 4] = k4;
                ushort4 v4 = *(const ushort4*)&Vg[(size_t)(j0 + row) * 64 + cg * 16 + i * 4];
                Vs[cg * 16 + i * 4 + 0][row] = v4.x;
                Vs[cg * 16 + i * 4 + 1][row] = v4.y;
                Vs[cg * 16 + i * 4 + 2][row] = v4.z;
                Vs[cg * 16 + i * 4 + 3][row] = v4.w;
            }
        }
        __syncthreads();

        // S = Q K^T  (16 q-rows x 64 kv-cols per wave)
        f32x4 sacc[4];
        #pragma unroll
        for (int nf = 0; nf < 4; ++nf) {
            bf16x8 b0 = *(const bf16x8*)&Ks[nf * 16 + (lane & 15)][(lane >> 4) * 8];
            bf16x8 b1 = *(const bf16x8*)&Ks[nf * 16 + (lane & 15)][32 + (lane >> 4) * 8];
            f32x4 z = (f32x4){0.f, 0.f, 0.f, 0.f};
            z = __builtin_amdgcn_mfma_f32_16x16x32_bf16(qf0, b0, z, 0, 0, 0);
            sacc[nf] = __builtin_amdgcn_mfma_f32_16x16x32_bf16(qf1, b1, z, 0, 0, 0);
        }
        if (jb == qb) {  // causal mask on diagonal tile
            #pragma unroll
            for (int nf = 0; nf < 4; ++nf)
                #pragma unroll
                for (int r = 0; r < 4; ++r) {
                    int j  = j0 + nf * 16 + (lane & 15);
                    int qr = q0 + wid * 16 + (lane >> 4) * 4 + r;
                    if (j > qr) sacc[nf][r] = -1e30f;
                }
        }
        // online softmax (row state replicated across each 16-lane group)
        float corr[4];
        #pragma unroll
        for (int r = 0; r < 4; ++r) {
            float mx = fmaxf(fmaxf(sacc[0][r], sacc[1][r]), fmaxf(sacc[2][r], sacc[3][r]));
            #pragma unroll
            for (int off = 1; off < 16; off <<= 1) mx = fmaxf(mx, __shfl_xor(mx, off, 64));
            float mnew = fmaxf(mrow[r], mx);
            corr[r] = __expf(mrow[r] - mnew);
            mrow[r] = mnew;
        }
        float psum[4] = {0.f, 0.f, 0.f, 0.f};
        #pragma unroll
        for (int nf = 0; nf < 4; ++nf)
            #pragma unroll
            for (int r = 0; r < 4; ++r) {
                float p = __expf(sacc[nf][r] - mrow[r]);
                psum[r] += p;
                Ps[wid][(lane >> 4) * 4 + r][nf * 16 + (lane & 15)] = f2bf(p);
            }
        #pragma unroll
        for (int r = 0; r < 4; ++r) {
            float s = psum[r];
            #pragma unroll
            for (int off = 1; off < 16; off <<= 1) s += __shfl_xor(s, off, 64);
            lrow[r] = lrow[r] * corr[r] + s;
        }
        #pragma unroll
        for (int kf = 0; kf < 4; ++kf)
            #pragma unroll
            for (int r = 0; r < 4; ++r) oacc[kf][r] *= corr[r];

        // PV: A = P strip (same-wave LDS round trip), B = Vs
        bf16x8 pa0 = *(const bf16x8*)&Ps[wid][lane & 15][(lane >> 4) * 8];
        bf16x8 pa1 = *(const bf16x8*)&Ps[wid][lane & 15][32 + (lane >> 4) * 8];
        #pragma unroll
        for (int kf = 0; kf < 4; ++kf) {
            bf16x8 v0 = *(const bf16x8*)&Vs[kf * 16 + (lane & 15)][(lane >> 4) * 8];
            bf16x8 v1 = *(const bf16x8*)&Vs[kf * 16 + (lane & 15)][32 + (lane >> 4) * 8];
            oacc[kf] = __builtin_amdgcn_mfma_f32_16x16x32_bf16(pa0, v0, oacc[kf], 0, 0, 0);
            oacc[kf] = __builtin_amdgcn_mfma_f32_16x16x32_bf16(pa1, v1, oacc[kf], 0, 0, 0);
        }
        __syncthreads();
    }

    const int bb = bh >> 4, h = bh & 15;
    #pragma unroll
    for (int kf = 0; kf < 4; ++kf)
        #pragma unroll
        for (int r = 0; r < 4; ++r) {
            int srow = q0 + wid * 16 + (lane >> 4) * 4 + r;
            float v = oacc[kf][r] / lrow[r];
            aout[((size_t)(bb * 2048 + srow)) * 1024 + h * 64 + kf * 16 + (lane & 15)] = f2bf(v);
        }
}

// ---------------------------------------------------------------------------
// Kernel 3: output projection. A[4096][1024] bf16 x Wproj[1024][1024] fp32
//   (+ b_proj) -> out fp32 [4096][1024].
// ---------------------------------------------------------------------------
__global__ __launch_bounds__(256) void proj_gemm(
    const unsigned short* __restrict__ A, const float* __restrict__ W,
    const float* __restrict__ bp, float* __restrict__ out)
{
    __shared__ unsigned short As[128][40];
    __shared__ unsigned short Bs[128][40];
    const int tid  = threadIdx.x;
    const int lane = tid & 63, wid = tid >> 6;
    const int wr = wid >> 1, wc = wid & 1;
    const int m0 = blockIdx.y * 128, n0 = blockIdx.x * 128;

    f32x4 acc[4][4];
    #pragma unroll
    for (int i = 0; i < 4; ++i)
        #pragma unroll
        for (int j = 0; j < 4; ++j) acc[i][j] = (f32x4){0.f, 0.f, 0.f, 0.f};

    for (int k0 = 0; k0 < 1024; k0 += 32) {
        #pragma unroll
        for (int p = 0; p < 4; ++p) {            // A tile (already bf16)
            int e = p * 1024 + tid * 4;
            int row = e >> 5, col = e & 31;
            *(ushort4*)&As[row][col] =
                *(const ushort4*)&A[(size_t)(m0 + row) * 1024 + k0 + col];
        }
        #pragma unroll
        for (int p = 0; p < 4; ++p) {            // W tile transposed -> Bs[n][k]
            int e = p * 1024 + tid * 4;
            int n = e & 127, kk = e >> 7;
            float4 v = *(const float4*)&W[(size_t)(k0 + kk) * 1024 + n0 + n];
            Bs[n + 0][kk] = f2bf(v.x);
            Bs[n + 1][kk] = f2bf(v.y);
            Bs[n + 2][kk] = f2bf(v.z);
            Bs[n + 3][kk] = f2bf(v.w);
        }
        __syncthreads();
        bf16x8 a[4], b[4];
        #pragma unroll
        for (int mi = 0; mi < 4; ++mi)
            a[mi] = *(const bf16x8*)&As[wr * 64 + mi * 16 + (lane & 15)][(lane >> 4) * 8];
        #pragma unroll
        for (int ni = 0; ni < 4; ++ni)
            b[ni] = *(const bf16x8*)&Bs[wc * 64 + ni * 16 + (lane & 15)][(lane >> 4) * 8];
        #pragma unroll
        for (int mi = 0; mi < 4; ++mi)
            #pragma unroll
            for (int ni = 0; ni < 4; ++ni)
                acc[mi][ni] = __builtin_amdgcn_mfma_f32_16x16x32_bf16(a[mi], b[ni], acc[mi][ni], 0, 0, 0);
        __syncthreads();
    }

    #pragma unroll
    for (int mi = 0; mi < 4; ++mi)
        #pragma unroll
        for (int ni = 0; ni < 4; ++ni)
            #pragma unroll
            for (int r = 0; r < 4; ++r) {
                int m = m0 + wr * 64 + mi * 16 + (lane >> 4) * 4 + r;
                int n = n0 + wc * 64 + ni * 16 + (lane & 15);
                out[(size_t)m * 1024 + n] = acc[mi][ni][r] + bp[n];
            }
}

extern "C" void kernel_launch(void* const* d_in, const int* in_sizes, int n_in,
                              void* d_out, int out_size, void* d_ws, size_t ws_size,
                              hipStream_t stream) {
    const float* x     = (const float*)d_in[0];
    // d_in[1] = mask (tril) — causality implemented directly
    const float* Wqkv  = (const float*)d_in[2];
    const float* bqkv  = (const float*)d_in[3];
    const float* Wproj = (const float*)d_in[4];
    const float* bproj = (const float*)d_in[5];

    unsigned short* qkv  = (unsigned short*)d_ws;            // 3 * QKV1 bf16 (24 MB)
    unsigned short* aout = qkv + 3 * (size_t)QKV1;           // 4096*1024 bf16 (8 MB)

    qkv_gemm<<<dim3(24, 32), 256, 0, stream>>>(x, Wqkv, bqkv, qkv);
    attn_fwd<<<dim3(32, 32), 256, 0, stream>>>(qkv, aout);
    proj_gemm<<<dim3(8, 32), 256, 0, stream>>>(aout, Wproj, bproj, (float*)d_out);
}

// Round 2
// 247.451 us; speedup vs baseline: 1.2914x; 1.2914x over previous
//
#include <hip/hip_runtime.h>

typedef __bf16 bf16x8 __attribute__((ext_vector_type(8)));
typedef float f32x4 __attribute__((ext_vector_type(4)));

constexpr int S_LEN = 2048;
constexpr int QKV1  = 2 * 16 * 2048 * 64;   // elements per Q/K/V tensor = 4194304

__device__ inline unsigned short f2bf(float f) {
    __bf16 h = (__bf16)f;
    return __builtin_bit_cast(unsigned short, h);
}

// ---------------------------------------------------------------------------
// Transpose + convert: src [R][C] fp32 -> dst [C][R] bf16
// ---------------------------------------------------------------------------
__global__ __launch_bounds__(256) void transpose_cvt(
    const float* __restrict__ src, unsigned short* __restrict__ dst, int R, int C)
{
    __shared__ float t[32][33];
    const int c0 = blockIdx.x * 32, r0 = blockIdx.y * 32;
    const int tx = threadIdx.x, ty = threadIdx.y;
    #pragma unroll
    for (int i = 0; i < 4; ++i)
        t[ty * 4 + i][tx] = src[(size_t)(r0 + ty * 4 + i) * C + c0 + tx];
    __syncthreads();
    #pragma unroll
    for (int i = 0; i < 4; ++i)
        dst[(size_t)(c0 + ty * 4 + i) * R + r0 + tx] = f2bf(t[tx][ty * 4 + i]);
}

// ---------------------------------------------------------------------------
// Kernel 1: QKV projection.  X[4096][1024] fp32 x Wt[3072][1024] bf16 (+bias)
//   -> Q,K,V bf16, each [B=2][H=16][S=2048][K=64], Q pre-scaled by 0.125.
// 128x128 tile, BK=64, 4 waves (2x2), each wave 64x64 via 4x4 16x16x32 MFMA.
// ---------------------------------------------------------------------------
__global__ __launch_bounds__(256) void qkv_gemm(
    const float* __restrict__ X, const unsigned short* __restrict__ Wt,
    const float* __restrict__ bq, unsigned short* __restrict__ qkv)
{
    __shared__ unsigned short As[128][88];   // stride 176B: 16B-aligned, b128 reads ~conflict-free
    __shared__ unsigned short Bs[128][88];
    const int tid  = threadIdx.x;
    const int lane = tid & 63, wid = tid >> 6;
    const int q = lane & 15, g = lane >> 4;
    const int wr = wid >> 1, wc = wid & 1;
    const int m0 = blockIdx.y * 128, n0 = blockIdx.x * 128;

    f32x4 acc[4][4];
    #pragma unroll
    for (int i = 0; i < 4; ++i)
        #pragma unroll
        for (int j = 0; j < 4; ++j) acc[i][j] = (f32x4){0.f, 0.f, 0.f, 0.f};

    for (int k0 = 0; k0 < 1024; k0 += 64) {
        #pragma unroll
        for (int p = 0; p < 8; ++p) {            // A tile 128x64 fp32 -> bf16
            int u = p * 256 + tid;
            int row = u >> 4, col = (u & 15) * 4;
            float4 v = *(const float4*)&X[(size_t)(m0 + row) * 1024 + k0 + col];
            ushort4 s;
            s.x = f2bf(v.x); s.y = f2bf(v.y); s.z = f2bf(v.z); s.w = f2bf(v.w);
            *(ushort4*)&As[row][col] = s;
        }
        #pragma unroll
        for (int p = 0; p < 4; ++p) {            // B tile 128x64 bf16 (pre-transposed)
            int u = p * 256 + tid;
            int row = u >> 2, col = (u & 3) * 16;
            ushort4 v0 = *(const ushort4*)&Wt[(size_t)(n0 + row) * 1024 + k0 + col];
            ushort4 v1 = *(const ushort4*)&Wt[(size_t)(n0 + row) * 1024 + k0 + col + 4];
            ushort4 v2 = *(const ushort4*)&Wt[(size_t)(n0 + row) * 1024 + k0 + col + 8];
            ushort4 v3 = *(const ushort4*)&Wt[(size_t)(n0 + row) * 1024 + k0 + col + 12];
            *(ushort4*)&Bs[row][col + 0]  = v0;
            *(ushort4*)&Bs[row][col + 4]  = v1;
            *(ushort4*)&Bs[row][col + 8]  = v2;
            *(ushort4*)&Bs[row][col + 12] = v3;
        }
        __syncthreads();
        #pragma unroll
        for (int h = 0; h < 2; ++h) {
            bf16x8 a[4], b[4];
            #pragma unroll
            for (int mi = 0; mi < 4; ++mi)
                a[mi] = *(const bf16x8*)&As[wr * 64 + mi * 16 + q][h * 32 + g * 8];
            #pragma unroll
            for (int ni = 0; ni < 4; ++ni)
                b[ni] = *(const bf16x8*)&Bs[wc * 64 + ni * 16 + q][h * 32 + g * 8];
            #pragma unroll
            for (int mi = 0; mi < 4; ++mi)
                #pragma unroll
                for (int ni = 0; ni < 4; ++ni)
                    acc[mi][ni] = __builtin_amdgcn_mfma_f32_16x16x32_bf16(a[mi], b[ni], acc[mi][ni], 0, 0, 0);
        }
        __syncthreads();
    }

    #pragma unroll
    for (int mi = 0; mi < 4; ++mi)
        #pragma unroll
        for (int ni = 0; ni < 4; ++ni)
            #pragma unroll
            for (int r = 0; r < 4; ++r) {
                int m = m0 + wr * 64 + mi * 16 + g * 4 + r;
                int n = n0 + wc * 64 + ni * 16 + q;
                float v = acc[mi][ni][r] + bq[n];
                int t = n >> 10, rem = n & 1023;
                if (t == 0) v *= 0.125f;          // q * rsqrt(64)
                int h = rem >> 6, kk = rem & 63;
                int bb = m >> 11, s = m & 2047;
                qkv[(size_t)t * QKV1 + ((size_t)(bb * 16 + h) * 2048 + s) * 64 + kk] = f2bf(v);
            }
}

// ---------------------------------------------------------------------------
// Kernel 2: causal flash attention. Block = (64 q-rows) x (one b,h).
// 4 waves x 16 q-rows. KV tiles of 64. Online softmax in registers.
// LPT dispatch (longest blocks first) + double-buffered K/V register prefetch.
// ---------------------------------------------------------------------------
__global__ __launch_bounds__(256) void attn_fwd(
    const unsigned short* __restrict__ qkv, unsigned short* __restrict__ aout)
{
    __shared__ unsigned short Ks[2][64][72];    // [buf][kv][k]
    __shared__ unsigned short Vs[2][64][72];    // [buf][k][kv] (transposed)
    __shared__ unsigned short Ps[4][16][72];    // per-wave P strip [qrow][kv]
    const int tid = threadIdx.x, lane = tid & 63, wid = tid >> 6;
    const int qb = 31 - blockIdx.x;             // LPT: longest blocks dispatch first
    const int bh = blockIdx.y;
    const int q0 = qb * 64;
    const unsigned short* Qg = qkv + (size_t)bh * S_LEN * 64;
    const unsigned short* Kg = qkv + (size_t)QKV1 + (size_t)bh * S_LEN * 64;
    const unsigned short* Vg = qkv + 2 * (size_t)QKV1 + (size_t)bh * S_LEN * 64;

    // Q fragments (A-operand: row = lane&15, k = (lane>>4)*8 + i)
    const int qrow_a = q0 + wid * 16 + (lane & 15);
    bf16x8 qf0 = *(const bf16x8*)&Qg[(size_t)qrow_a * 64 + (lane >> 4) * 8];
    bf16x8 qf1 = *(const bf16x8*)&Qg[(size_t)qrow_a * 64 + 32 + (lane >> 4) * 8];

    f32x4 oacc[4];
    #pragma unroll
    for (int i = 0; i < 4; ++i) oacc[i] = (f32x4){0.f, 0.f, 0.f, 0.f};
    float mrow[4], lrow[4];
    #pragma unroll
    for (int r = 0; r < 4; ++r) { mrow[r] = -1e30f; lrow[r] = 0.f; }

    const int srow_st = tid >> 2, scg = tid & 3;
    ushort4 kreg[4], vreg[4];
    auto stage_load = [&](int j0) {
        #pragma unroll
        for (int i = 0; i < 4; ++i) {
            kreg[i] = *(const ushort4*)&Kg[(size_t)(j0 + srow_st) * 64 + scg * 16 + i * 4];
            vreg[i] = *(const ushort4*)&Vg[(size_t)(j0 + srow_st) * 64 + scg * 16 + i * 4];
        }
    };
    auto stage_write = [&](int b) {
        #pragma unroll
        for (int i = 0; i < 4; ++i) {
            *(ushort4*)&Ks[b][srow_st][scg * 16 + i * 4] = kreg[i];
            Vs[b][scg * 16 + i * 4 + 0][srow_st] = vreg[i].x;
            Vs[b][scg * 16 + i * 4 + 1][srow_st] = vreg[i].y;
            Vs[b][scg * 16 + i * 4 + 2][srow_st] = vreg[i].z;
            Vs[b][scg * 16 + i * 4 + 3][srow_st] = vreg[i].w;
        }
    };

    stage_load(0);
    stage_write(0);
    int cur = 0;

    for (int jb = 0; jb <= qb; ++jb) {
        const int j0 = jb * 64;
        const bool pf = (jb < qb);
        if (pf) stage_load(j0 + 64);             // issue next tile's loads early
        __syncthreads();                          // buf[cur] writes complete

        // S = Q K^T  (16 q-rows x 64 kv-cols per wave)
        f32x4 sacc[4];
        #pragma unroll
        for (int nf = 0; nf < 4; ++nf) {
            bf16x8 b0 = *(const bf16x8*)&Ks[cur][nf * 16 + (lane & 15)][(lane >> 4) * 8];
            bf16x8 b1 = *(const bf16x8*)&Ks[cur][nf * 16 + (lane & 15)][32 + (lane >> 4) * 8];
            f32x4 z = (f32x4){0.f, 0.f, 0.f, 0.f};
            z = __builtin_amdgcn_mfma_f32_16x16x32_bf16(qf0, b0, z, 0, 0, 0);
            sacc[nf] = __builtin_amdgcn_mfma_f32_16x16x32_bf16(qf1, b1, z, 0, 0, 0);
        }
        if (jb == qb) {  // causal mask on diagonal tile
            #pragma unroll
            for (int nf = 0; nf < 4; ++nf)
                #pragma unroll
                for (int r = 0; r < 4; ++r) {
                    int j  = j0 + nf * 16 + (lane & 15);
                    int qr = q0 + wid * 16 + (lane >> 4) * 4 + r;
                    if (j > qr) sacc[nf][r] = -1e30f;
                }
        }
        // online softmax (row state replicated across each 16-lane group)
        float corr[4];
        #pragma unroll
        for (int r = 0; r < 4; ++r) {
            float mx = fmaxf(fmaxf(sacc[0][r], sacc[1][r]), fmaxf(sacc[2][r], sacc[3][r]));
            #pragma unroll
            for (int off = 1; off < 16; off <<= 1) mx = fmaxf(mx, __shfl_xor(mx, off, 64));
            float mnew = fmaxf(mrow[r], mx);
            corr[r] = __expf(mrow[r] - mnew);
            mrow[r] = mnew;
        }
        float psum[4] = {0.f, 0.f, 0.f, 0.f};
        #pragma unroll
        for (int nf = 0; nf < 4; ++nf)
            #pragma unroll
            for (int r = 0; r < 4; ++r) {
                float p = __expf(sacc[nf][r] - mrow[r]);
                psum[r] += p;
                Ps[wid][(lane >> 4) * 4 + r][nf * 16 + (lane & 15)] = f2bf(p);
            }
        #pragma unroll
        for (int r = 0; r < 4; ++r) {
            float s = psum[r];
            #pragma unroll
            for (int off = 1; off < 16; off <<= 1) s += __shfl_xor(s, off, 64);
            lrow[r] = lrow[r] * corr[r] + s;
        }
        #pragma unroll
        for (int kf = 0; kf < 4; ++kf)
            #pragma unroll
            for (int r = 0; r < 4; ++r) oacc[kf][r] *= corr[r];

        // PV: A = P strip (same-wave LDS round trip), B = Vs
        bf16x8 pa0 = *(const bf16x8*)&Ps[wid][lane & 15][(lane >> 4) * 8];
        bf16x8 pa1 = *(const bf16x8*)&Ps[wid][lane & 15][32 + (lane >> 4) * 8];
        #pragma unroll
        for (int kf = 0; kf < 4; ++kf) {
            bf16x8 v0 = *(const bf16x8*)&Vs[cur][kf * 16 + (lane & 15)][(lane >> 4) * 8];
            bf16x8 v1 = *(const bf16x8*)&Vs[cur][kf * 16 + (lane & 15)][32 + (lane >> 4) * 8];
            oacc[kf] = __builtin_amdgcn_mfma_f32_16x16x32_bf16(pa0, v0, oacc[kf], 0, 0, 0);
            oacc[kf] = __builtin_amdgcn_mfma_f32_16x16x32_bf16(pa1, v1, oacc[kf], 0, 0, 0);
        }

        if (pf) stage_write(cur ^ 1);            // write-late: HBM latency hidden by compute
        cur ^= 1;
    }

    const int bb = bh >> 4, h = bh & 15;
    #pragma unroll
    for (int kf = 0; kf < 4; ++kf)
        #pragma unroll
        for (int r = 0; r < 4; ++r) {
            int srow = q0 + wid * 16 + (lane >> 4) * 4 + r;
            float v = oacc[kf][r] / lrow[r];
            aout[((size_t)(bb * 2048 + srow)) * 1024 + h * 64 + kf * 16 + (lane & 15)] = f2bf(v);
        }
}

// ---------------------------------------------------------------------------
// Kernel 3: output projection. A[4096][1024] bf16 x Wt2[1024][1024] bf16
//   (+ b_proj) -> out fp32 [4096][1024].  BK=64, all-bf16 staging.
// ---------------------------------------------------------------------------
__global__ __launch_bounds__(256) void proj_gemm(
    const unsigned short* __restrict__ A, const unsigned short* __restrict__ Wt2,
    const float* __restrict__ bp, float* __restrict__ out)
{
    __shared__ unsigned short As[128][88];
    __shared__ unsigned short Bs[128][88];
    const int tid  = threadIdx.x;
    const int lane = tid & 63, wid = tid >> 6;
    const int q = lane & 15, g = lane >> 4;
    const int wr = wid >> 1, wc = wid & 1;
    const int m0 = blockIdx.y * 128, n0 = blockIdx.x * 128;

    f32x4 acc[4][4];
    #pragma unroll
    for (int i = 0; i < 4; ++i)
        #pragma unroll
        for (int j = 0; j < 4; ++j) acc[i][j] = (f32x4){0.f, 0.f, 0.f, 0.f};

    for (int k0 = 0; k0 < 1024; k0 += 64) {
        #pragma unroll
        for (int p = 0; p < 4; ++p) {
            int u = p * 256 + tid;
            int row = u >> 2, col = (u & 3) * 16;
            #pragma unroll
            for (int c = 0; c < 4; ++c)
                *(ushort4*)&As[row][col + c * 4] =
                    *(const ushort4*)&A[(size_t)(m0 + row) * 1024 + k0 + col + c * 4];
        }
        #pragma unroll
        for (int p = 0; p < 4; ++p) {
            int u = p * 256 + tid;
            int row = u >> 2, col = (u & 3) * 16;
            #pragma unroll
            for (int c = 0; c < 4; ++c)
                *(ushort4*)&Bs[row][col + c * 4] =
                    *(const ushort4*)&Wt2[(size_t)(n0 + row) * 1024 + k0 + col + c * 4];
        }
        __syncthreads();
        #pragma unroll
        for (int h = 0; h < 2; ++h) {
            bf16x8 a[4], b[4];
            #pragma unroll
            for (int mi = 0; mi < 4; ++mi)
                a[mi] = *(const bf16x8*)&As[wr * 64 + mi * 16 + q][h * 32 + g * 8];
            #pragma unroll
            for (int ni = 0; ni < 4; ++ni)
                b[ni] = *(const bf16x8*)&Bs[wc * 64 + ni * 16 + q][h * 32 + g * 8];
            #pragma unroll
            for (int mi = 0; mi < 4; ++mi)
                #pragma unroll
                for (int ni = 0; ni < 4; ++ni)
                    acc[mi][ni] = __builtin_amdgcn_mfma_f32_16x16x32_bf16(a[mi], b[ni], acc[mi][ni], 0, 0, 0);
        }
        __syncthreads();
    }

    #pragma unroll
    for (int mi = 0; mi < 4; ++mi)
        #pragma unroll
        for (int ni = 0; ni < 4; ++ni)
            #pragma unroll
            for (int r = 0; r < 4; ++r) {
                int m = m0 + wr * 64 + mi * 16 + g * 4 + r;
                int n = n0 + wc * 64 + ni * 16 + q;
                out[(size_t)m * 1024 + n] = acc[mi][ni][r] + bp[n];
            }
}

extern "C" void kernel_launch(void* const* d_in, const int* in_sizes, int n_in,
                              void* d_out, int out_size, void* d_ws, size_t ws_size,
                              hipStream_t stream) {
    const float* x     = (const float*)d_in[0];
    // d_in[1] = mask (tril) — causality implemented directly
    const float* Wqkv  = (const float*)d_in[2];
    const float* bqkv  = (const float*)d_in[3];
    const float* Wproj = (const float*)d_in[4];
    const float* bproj = (const float*)d_in[5];

    unsigned short* qkvb = (unsigned short*)d_ws;            // 3*QKV1 bf16 (25.2 MB)
    unsigned short* aoutb = qkvb + 3 * (size_t)QKV1;         // 4096*1024 bf16 (8.4 MB)
    // Region reuse (stream-serial, zero extra ws):
    unsigned short* Wt  = aoutb;   // W_qkv^T bf16 [3072][1024] (6.3 MB) — dead once attn writes aout
    unsigned short* Wt2 = qkvb;    // W_proj^T bf16 [1024][1024] (2.1 MB) — qkv dead after attn

    transpose_cvt<<<dim3(96, 32), dim3(32, 8), 0, stream>>>(Wqkv, Wt, 1024, 3072);
    qkv_gemm<<<dim3(24, 32), 256, 0, stream>>>(x, Wt, bqkv, qkvb);
    attn_fwd<<<dim3(32, 32), 256, 0, stream>>>(qkvb, aoutb);
    transpose_cvt<<<dim3(32, 32), dim3(32, 8), 0, stream>>>(Wproj, Wt2, 1024, 1024);
    proj_gemm<<<dim3(8, 32), 256, 0, stream>>>(aoutb, Wt2, bproj, (float*)d_out);
}